// Round 13
// baseline (116.268 us; speedup 1.0000x reference)
//
#include <hip/hip_runtime.h>
#include <hip/hip_bf16.h>

#define S_DIM 1024
#define B_DIM 4
#define D_DIM 1024
#define H_DIM 16
#define DH    64
#define T_DIM (S_DIM * B_DIM)   // 4096
#define QKV_N (3 * D_DIM)       // 3072

using bf16 = __hip_bfloat16;
typedef __attribute__((ext_vector_type(4))) float fx4;
typedef __attribute__((ext_vector_type(8))) short bx8;

__device__ __forceinline__ unsigned short f2bf(float f) {
  union { float f; unsigned int u; } cv; cv.f = f;
  unsigned int u = cv.u;
  unsigned int r = (u + 0x7FFFu + ((u >> 16) & 1u)) >> 16;  // RNE
  return (unsigned short)r;
}

__device__ __forceinline__ void g2l16(const void* g, void* l) {
  __builtin_amdgcn_global_load_lds(
      (const __attribute__((address_space(1))) unsigned int*)g,
      (__attribute__((address_space(3))) unsigned int*)l, 16, 0, 0);
}

// ---------------- prep: LN1->bf16 (blocks 0..4095) + weight casts ----------
__global__ __launch_bounds__(256) void prep_kernel(
    const float* __restrict__ x, const float* __restrict__ w,
    const float* __restrict__ bb, bf16* __restrict__ out,
    const float* __restrict__ win, bf16* __restrict__ winb,
    const float* __restrict__ wout, bf16* __restrict__ woutb) {
  const int blk = blockIdx.x, tid = threadIdx.x;
  if (blk >= 4096) {  // weight cast: 1048576 fx4 chunks total
    const int i = (blk - 4096) * 256 + tid;
    const float* src; bf16* dst; int j;
    if (i < 786432) { src = win; dst = winb; j = i; }
    else { src = wout; dst = woutb; j = i - 786432; }
    const fx4 v = ((const fx4*)src)[j];
    ushort4 u;
    u.x = f2bf(v[0]); u.y = f2bf(v[1]); u.z = f2bf(v[2]); u.w = f2bf(v[3]);
    ((ushort4*)dst)[j] = u;
    return;
  }
  const int t = blk;
  const fx4 v = ((const fx4*)(x + (size_t)t * D_DIM))[tid];
  float s  = v[0] + v[1] + v[2] + v[3];
  float ss = v[0]*v[0] + v[1]*v[1] + v[2]*v[2] + v[3]*v[3];
#pragma unroll
  for (int off = 32; off >= 1; off >>= 1) {
    s  += __shfl_xor(s, off);
    ss += __shfl_xor(ss, off);
  }
  __shared__ float red[8];
  const int wid = tid >> 6, lane = tid & 63;
  if (lane == 0) { red[wid] = s; red[4 + wid] = ss; }
  __syncthreads();
  s  = red[0] + red[1] + red[2] + red[3];
  ss = red[4] + red[5] + red[6] + red[7];
  const float mu = s * (1.f / D_DIM);
  const float rstd = rsqrtf(ss * (1.f / D_DIM) - mu * mu + 1e-5f);
  const fx4 wv = ((const fx4*)w)[tid];
  const fx4 bv = ((const fx4*)bb)[tid];
  ushort4 u;
  u.x = f2bf((v[0] - mu) * rstd * wv[0] + bv[0]);
  u.y = f2bf((v[1] - mu) * rstd * wv[1] + bv[1]);
  u.z = f2bf((v[2] - mu) * rstd * wv[2] + bv[2]);
  u.w = f2bf((v[3] - mu) * rstd * wv[3] + bv[3]);
  ((ushort4*)(out + (size_t)t * D_DIM))[tid] = u;
}

// ---------------- qkv GEMM: 128x128, 3-deep, ONE barrier/iter --------------
// Main loop at structural ceiling (rounds 4/7/8/10: 39.3 us). Epilogue now
// writes v DIRECTLY TRANSPOSED into vt[bh][dh][s] (round-9-validated
// indexing) -> transpose_v kernel deleted (-16MB read, -16MB write).
// q/k written bf16 [bh][s][64]; q pre-scaled by 0.125*log2(e).
__global__ __launch_bounds__(256, 3) void gemm_qkv(
    const bf16* __restrict__ A, const bf16* __restrict__ B,
    const float* __restrict__ bias, ushort* __restrict__ qkvb,
    ushort* __restrict__ vt, int K) {
  __shared__ char sA[3][8192];
  __shared__ char sB[3][8192];
  const int tid  = threadIdx.x;
  const int brow = blockIdx.y * 128;
  const int bcol = blockIdx.x * 128;
  const int wid  = tid >> 6;
  const int lane = tid & 63;
  const int wr   = wid >> 1;
  const int wc   = wid & 1;
  const int fr   = lane & 15;
  const int fk   = lane >> 4;

  fx4 acc[4][4];
#pragma unroll
  for (int i = 0; i < 4; ++i)
#pragma unroll
    for (int j = 0; j < 4; ++j) acc[i][j] = 0.f;

  const int arow = tid >> 2;                       // 0..63
  const int gch  = (tid & 3) ^ ((arow >> 1) & 3);  // inverse-swizzled chunk

  auto stage = [&](int buf, int kt) {
#pragma unroll
    for (int is = 0; is < 2; ++is) {
      const int row = is * 64 + arow;
      g2l16(A + (size_t)(brow + row) * K + kt + gch * 8,
            sA[buf] + is * 4096 + tid * 16);
      g2l16(B + (size_t)(bcol + row) * K + kt + gch * 8,
            sB[buf] + is * 4096 + tid * 16);
    }
  };

  stage(0, 0);
  stage(1, 32);

  const int nk = K >> 5;   // 32
#pragma unroll 1
  for (int ki = 0; ki < nk; ++ki) {
    const int buf = ki % 3;
    if (ki + 1 < nk) {
      asm volatile("s_waitcnt vmcnt(4)" ::: "memory");   // tile ki landed
    } else {
      asm volatile("s_waitcnt vmcnt(0)" ::: "memory");
    }
    __builtin_amdgcn_s_barrier();   // collective + WAR for buf[(ki+2)%3]
    asm volatile("" ::: "memory");
    if (ki + 2 < nk) stage((ki + 2) % 3, (ki + 2) * 32);

    bx8 af[4], bfr[4];
#pragma unroll
    for (int mm = 0; mm < 4; ++mm) {
      const int ar = wr * 64 + mm * 16 + fr;
      af[mm] = *(const bx8*)(sA[buf] + ar * 64 + ((fk ^ ((ar >> 1) & 3)) << 4));
    }
#pragma unroll
    for (int nn = 0; nn < 4; ++nn) {
      const int br = wc * 64 + nn * 16 + fr;
      bfr[nn] = *(const bx8*)(sB[buf] + br * 64 + ((fk ^ ((br >> 1) & 3)) << 4));
    }
    __builtin_amdgcn_s_setprio(1);
#pragma unroll
    for (int mm = 0; mm < 4; ++mm)
#pragma unroll
      for (int nn = 0; nn < 4; ++nn)
        acc[mm][nn] = __builtin_amdgcn_mfma_f32_16x16x32_bf16(
            af[mm], bfr[nn], acc[mm][nn], 0, 0, 0);
    __builtin_amdgcn_s_setprio(0);
    asm volatile("" ::: "memory");
  }

  // C/D layout: col = lane&15, row = (lane>>4)*4 + reg
  const int row0 = brow + wr * 64 + fk * 4;
  const int col0 = bcol + wc * 64 + fr;
#pragma unroll
  for (int mm = 0; mm < 4; ++mm) {
#pragma unroll
    for (int nn = 0; nn < 4; ++nn) {
      const int col = col0 + nn * 16;
      const float bv = bias[col];
      const int which = col >> 10;          // 0=q 1=k 2=v
      const int rem   = col & 1023;
      const int hh    = rem >> 6;
      const int dh    = rem & 63;
      // q scaled by DH^-0.5 * log2(e): softmax runs in exp2 domain
      const float scale = (which == 0) ? 0.18033688f : 1.0f;
#pragma unroll
      for (int rr = 0; rr < 4; ++rr) {
        const int row = row0 + mm * 16 + rr;  // t = s*B + b
        const int ss2 = row >> 2, bb2 = row & 3;
        const float v = (acc[mm][nn][rr] + bv) * scale;
        const unsigned short bvv = f2bf(v);
        if (which == 2) {  // v written directly transposed: vt[bh][dh][s]
          vt[(size_t)(bb2 * 16 + hh) * 65536 + (size_t)dh * 1024 + ss2] = bvv;
        } else {
          qkvb[(size_t)which * 4194304 +
               ((size_t)(bb2 * 16 + hh)) * 65536 + (size_t)ss2 * 64 + dh] = bvv;
        }
      }
    }
  }
}

// ---------------- MFMA flash attention: 2 q-tiles share K/V staging --------
// 512-thread block: waves 0-3 own q-tile 2p, waves 4-7 own 2p+1. One K/VT
// stage per iter serves both tiles. Grid 512 = 2 blocks/CU resident.
// Swapped S^T = mfma(K,Q); exp2-domain softmax; truncating bf16 P-pack;
// 2-phase counted-vmcnt pipeline; defer-max; setprio.
__global__ __launch_bounds__(512, 4) void attn_mfma(
    const ushort* __restrict__ qb, const ushort* __restrict__ kb,
    const ushort* __restrict__ vtb, ushort* __restrict__ ob) {
  __shared__ __align__(16) char sK[2][8192];
  __shared__ __align__(16) char sVT[2][8192];
  __shared__ __align__(16) char sP[16384];
  const int tid  = threadIdx.x;
  const int wid  = tid >> 6;        // 0..7
  const int lane = tid & 63;
  const int bid  = blockIdx.x;
  const int pi   = 7 - (bid >> 6);  // pair index, longest (pi=7) first
  const int bh   = bid & 63;
  const int b    = bh >> 4, h = bh & 15;
  const int fr   = lane & 15;
  const int fk   = lane >> 4;
  const size_t bhoff = (size_t)bh * 65536;
  char* const sPw = sP + wid * 2048;
  const int swp = (fr & 7) << 4;
  const int qt_lo   = 2 * pi;
  const int qt_max  = 2 * pi + 1;   // = qt_hi
  const int qt_mine = (wid < 4) ? qt_lo : qt_max;
  const int wid4 = wid & 3;

  auto stage = [&](int buf, int k0) {
    const int L    = tid * 16;
    const int row  = L >> 7;
    const int colb = (L & 127) ^ ((row & 7) << 4);
    g2l16(kb  + bhoff + (size_t)(k0 + row) * 64 + (colb >> 1), sK[buf]  + L);
    g2l16(vtb + bhoff + (size_t)row * 1024 + k0 + (colb >> 1), sVT[buf] + L);
  };

  const int q0w = qt_mine * 64 + wid4 * 16;
  const ushort* qp = qb + bhoff + (size_t)(q0w + fr) * 64;
  const bx8 qf0 = *(const bx8*)(qp + fk * 8);
  const bx8 qf1 = *(const bx8*)(qp + 32 + fk * 8);
  asm volatile("s_waitcnt vmcnt(0)" ::: "memory");  // exact vmcnt counting

  fx4 o4[4];
  float m = -3e38f, l = 0.f;
#pragma unroll
  for (int dt = 0; dt < 4; ++dt) o4[dt] = 0.f;

  stage(0, 0);   // 2 loads/thread outstanding

#pragma unroll 1
  for (int kbk = 0; kbk <= qt_max; ++kbk) {
    const int cur = kbk & 1;
    if (kbk < qt_max) {
      stage(cur ^ 1, (kbk + 1) * 64);                   // +2 -> 4 outstanding
      asm volatile("s_waitcnt vmcnt(2)" ::: "memory");  // cur's 2 landed
    } else {
      asm volatile("s_waitcnt vmcnt(0)" ::: "memory");
    }
    __builtin_amdgcn_s_barrier();
    asm volatile("" ::: "memory");

    if (kbk <= qt_mine) {   // wave-uniform guard; no barriers inside
      const char* sKc  = sK[cur];
      const char* sVTc = sVT[cur];

      // --- S^T = mfma(K, Q): s4[kt][rr] = S[key=kt*16+fk*4+rr][q=fr] ---
      fx4 s4[4];
      __builtin_amdgcn_s_setprio(1);
#pragma unroll
      for (int kt = 0; kt < 4; ++kt) {
        const int krow = kt * 16 + fr;
        const int sw   = (krow & 7) << 4;
        const bx8 kf0 = *(const bx8*)(sKc + krow * 128 + ((fk * 16) ^ sw));
        const bx8 kf1 = *(const bx8*)(sKc + krow * 128 + ((64 + fk * 16) ^ sw));
        fx4 z = {0.f, 0.f, 0.f, 0.f};
        z = __builtin_amdgcn_mfma_f32_16x16x32_bf16(kf0, qf0, z, 0, 0, 0);
        s4[kt] = __builtin_amdgcn_mfma_f32_16x16x32_bf16(kf1, qf1, z, 0, 0, 0);
      }
      __builtin_amdgcn_s_setprio(0);

      if (kbk == qt_mine) {  // diagonal: wave-relative causal mask
        const int qloc = wid4 * 16 + fr;
#pragma unroll
        for (int kt = 0; kt < 4; ++kt) {
          const int keyb = kt * 16 + fk * 4;
#pragma unroll
          for (int rr = 0; rr < 4; ++rr)
            if (keyb + rr > qloc) s4[kt][rr] = -3e38f;
        }
      }

      // --- online softmax in exp2 domain: lane owns q=fr ---
      float pm = s4[0][0];
#pragma unroll
      for (int kt = 0; kt < 4; ++kt)
#pragma unroll
        for (int rr = 0; rr < 4; ++rr) pm = fmaxf(pm, s4[kt][rr]);
      pm = fmaxf(pm, __shfl_xor(pm, 16));
      pm = fmaxf(pm, __shfl_xor(pm, 32));

      if (__any(pm > m + 11.5f)) {   // defer-max (T13)
        const float mn = fmaxf(m, pm);
        const float f  = exp2f(m - mn);
        m = mn;
        l *= f;
        float fq[4];
#pragma unroll
        for (int rr = 0; rr < 4; ++rr) fq[rr] = __shfl(f, fk * 4 + rr);
#pragma unroll
        for (int dt = 0; dt < 4; ++dt)
#pragma unroll
          for (int rr = 0; rr < 4; ++rr) o4[dt][rr] *= fq[rr];
      }

      // --- P = exp2(S-m), truncating bf16 pack, b64 LDS writes ---
#pragma unroll
      for (int kt = 0; kt < 4; ++kt) {
        union { float f; unsigned u; } a0, a1, a2, a3;
        a0.f = exp2f(s4[kt][0] - m);
        a1.f = exp2f(s4[kt][1] - m);
        a2.f = exp2f(s4[kt][2] - m);
        a3.f = exp2f(s4[kt][3] - m);
        l += (a0.f + a1.f) + (a2.f + a3.f);
        uint2 pk;
        pk.x = (a0.u >> 16) | (a1.u & 0xFFFF0000u);
        pk.y = (a2.u >> 16) | (a3.u & 0xFFFF0000u);
        *(uint2*)(sPw + ((fr * 128 + kt * 32 + fk * 8) ^ swp)) = pk;
      }

      // --- O += P V ---
      __builtin_amdgcn_s_setprio(1);
#pragma unroll
      for (int c = 0; c < 2; ++c) {
        const bx8 pa = *(const bx8*)(sPw + ((fr * 128 + c * 64 + fk * 16) ^ swp));
#pragma unroll
        for (int dt = 0; dt < 4; ++dt) {
          const int vrow = dt * 16 + fr;
          const bx8 vf = *(const bx8*)(sVTc + vrow * 128 +
                                       ((c * 64 + fk * 16) ^ ((vrow & 7) << 4)));
          o4[dt] = __builtin_amdgcn_mfma_f32_16x16x32_bf16(pa, vf, o4[dt], 0, 0, 0);
        }
      }
      __builtin_amdgcn_s_setprio(0);
    }

    asm volatile("" ::: "memory");
    __builtin_amdgcn_s_barrier();   // readers done before next overwrite
    asm volatile("" ::: "memory");
  }

  // --- epilogue: total row sums, per-output-row norms, store ---
  l += __shfl_xor(l, 16);
  l += __shfl_xor(l, 32);
  const float linv = 1.f / l;
  float lq[4];
#pragma unroll
  for (int rr = 0; rr < 4; ++rr) lq[rr] = __shfl(linv, fk * 4 + rr);

#pragma unroll
  for (int dt = 0; dt < 4; ++dt) {
#pragma unroll
    for (int rr = 0; rr < 4; ++rr) {
      const int qq = q0w + fk * 4 + rr;
      ob[((size_t)qq * 4 + b) * 1024 + h * 64 + dt * 16 + fr] =
          f2bf(o4[dt][rr] * lq[rr]);
    }
  }
}

// ---------------- out-proj GEMM: 128x64, 3-deep, ONE barrier/iter ----------
__global__ __launch_bounds__(256, 2) void gemm_out(
    const bf16* __restrict__ A, const bf16* __restrict__ B,
    const float* __restrict__ bias, const float* __restrict__ resid,
    float* __restrict__ C) {
  __shared__ char sA[3][8192];
  __shared__ char sB[3][4096];
  const int tid  = threadIdx.x;
  const int brow = blockIdx.y * 128;
  const int bcol = blockIdx.x * 64;
  const int wid  = tid >> 6;
  const int lane = tid & 63;
  const int wr   = wid >> 1;      // 0..1: 64-row stripe
  const int wc   = wid & 1;       // 0..1: 32-col stripe
  const int fr   = lane & 15;
  const int fk   = lane >> 4;

  fx4 acc[4][2];
#pragma unroll
  for (int i = 0; i < 4; ++i)
#pragma unroll
    for (int j = 0; j < 2; ++j) acc[i][j] = 0.f;

  const int arow = tid >> 2;
  const int gch  = (tid & 3) ^ ((arow >> 1) & 3);

  auto stage = [&](int buf, int kt) {
#pragma unroll
    for (int is = 0; is < 2; ++is) {
      const int row = is * 64 + arow;
      g2l16(A + (size_t)(brow + row) * 1024 + kt + gch * 8,
            sA[buf] + is * 4096 + tid * 16);
    }
    g2l16(B + (size_t)(bcol + arow) * 1024 + kt + gch * 8,
          sB[buf] + tid * 16);
  };

  stage(0, 0);
  stage(1, 32);

#pragma unroll 1
  for (int ki = 0; ki < 32; ++ki) {
    const int buf = ki % 3;
    if (ki + 1 < 32) {
      asm volatile("s_waitcnt vmcnt(3)" ::: "memory");
    } else {
      asm volatile("s_waitcnt vmcnt(0)" ::: "memory");
    }
    __builtin_amdgcn_s_barrier();
    asm volatile("" ::: "memory");
    if (ki + 2 < 32) stage((ki + 2) % 3, (ki + 2) * 32);

    bx8 af[4], bfr[2];
#pragma unroll
    for (int mm = 0; mm < 4; ++mm) {
      const int ar = wr * 64 + mm * 16 + fr;
      af[mm] = *(const bx8*)(sA[buf] + ar * 64 + ((fk ^ ((ar >> 1) & 3)) << 4));
    }
#pragma unroll
    for (int nn = 0; nn < 2; ++nn) {
      const int br = wc * 32 + nn * 16 + fr;
      bfr[nn] = *(const bx8*)(sB[buf] + br * 64 + ((fk ^ ((br >> 1) & 3)) << 4));
    }
    __builtin_amdgcn_s_setprio(1);
#pragma unroll
    for (int mm = 0; mm < 4; ++mm)
#pragma unroll
      for (int nn = 0; nn < 2; ++nn)
        acc[mm][nn] = __builtin_amdgcn_mfma_f32_16x16x32_bf16(
            af[mm], bfr[nn], acc[mm][nn], 0, 0, 0);
    __builtin_amdgcn_s_setprio(0);
    asm volatile("" ::: "memory");
  }

  const int row0 = brow + wr * 64 + fk * 4;
  const int col0 = bcol + wc * 32 + fr;
#pragma unroll
  for (int mm = 0; mm < 4; ++mm) {
#pragma unroll
    for (int nn = 0; nn < 2; ++nn) {
      const int col = col0 + nn * 16;
      const float bv = bias[col];
#pragma unroll
      for (int rr = 0; rr < 4; ++rr) {
        const int row = row0 + mm * 16 + rr;
        C[(size_t)row * 1024 + col] =
            acc[mm][nn][rr] + bv + resid[(size_t)row * 1024 + col];
      }
    }
  }
}

// ---------------- LN2 + router + gate + final multiply ----------------
__global__ __launch_bounds__(256) void final_kernel(
    const float* __restrict__ xn, const float* __restrict__ w,
    const float* __restrict__ bb, const float* __restrict__ gw,
    float* __restrict__ out, float* __restrict__ rlog) {
  const int t = blockIdx.x, tid = threadIdx.x;
  const fx4 v = ((const fx4*)(xn + (size_t)t * D_DIM))[tid];
  float s  = v[0] + v[1] + v[2] + v[3];
  float ss = v[0]*v[0] + v[1]*v[1] + v[2]*v[2] + v[3]*v[3];
#pragma unroll
  for (int off = 32; off >= 1; off >>= 1) {
    s  += __shfl_xor(s, off);
    ss += __shfl_xor(ss, off);
  }
  __shared__ float red[8];
  __shared__ float red2[12];
  const int wid = tid >> 6, lane = tid & 63;
  if (lane == 0) { red[wid] = s; red[4 + wid] = ss; }
  __syncthreads();
  s  = red[0] + red[1] + red[2] + red[3];
  ss = red[4] + red[5] + red[6] + red[7];
  const float mu = s * (1.f / D_DIM);
  const float rstd = rsqrtf(ss * (1.f / D_DIM) - mu * mu + 1e-5f);
  const fx4 wv = ((const fx4*)w)[tid];
  const fx4 bv = ((const fx4*)bb)[tid];
  fx4 hv;
#pragma unroll
  for (int cc = 0; cc < 4; ++cc) hv[cc] = (v[cc] - mu) * rstd * wv[cc] + bv[cc];

  const fx4 w0 = ((const fx4*)(gw           ))[tid];
  const fx4 w1 = ((const fx4*)(gw +     D_DIM))[tid];
  const fx4 w2 = ((const fx4*)(gw + 2 * D_DIM))[tid];
  float g0 = hv[0]*w0[0] + hv[1]*w0[1] + hv[2]*w0[2] + hv[3]*w0[3];
  float g1 = hv[0]*w1[0] + hv[1]*w1[1] + hv[2]*w1[2] + hv[3]*w1[3];
  float g2 = hv[0]*w2[0] + hv[1]*w2[1] + hv[2]*w2[2] + hv[3]*w2[3];
#pragma unroll
  for (int off = 32; off >= 1; off >>= 1) {
    g0 += __shfl_xor(g0, off);
    g1 += __shfl_xor(g1, off);
    g2 += __shfl_xor(g2, off);
  }
  if (lane == 0) { red2[wid] = g0; red2[4 + wid] = g1; red2[8 + wid] = g2; }
  __syncthreads();
  g0 = red2[0] + red2[1] + red2[2]  + red2[3];
  g1 = red2[4] + red2[5] + red2[6]  + red2[7];
  g2 = red2[8] + red2[9] + red2[10] + red2[11];

  // gate = pmax/(pmax+p2nd) of softmax over 3 = 1/(1+exp(l_mid - l_max))
  const float lmax = fmaxf(g0, fmaxf(g1, g2));
  const float lmin = fminf(g0, fminf(g1, g2));
  const float lmid = (g0 + g1 + g2) - lmax - lmin;
  const float gate = 1.f / (1.f + __expf(lmid - lmax));

  ((fx4*)(out + (size_t)t * D_DIM))[tid] = v * gate;
  if (tid == 0) {
    rlog[(size_t)t * 3 + 0] = g0;
    rlog[(size_t)t * 3 + 1] = g1;
    rlog[(size_t)t * 3 + 2] = g2;
  }
}

extern "C" void kernel_launch(void* const* d_in, const int* in_sizes, int n_in,
                              void* d_out, int out_size, void* d_ws, size_t ws_size,
                              hipStream_t stream) {
  (void)in_sizes; (void)n_in; (void)out_size; (void)ws_size;
  const float* x    = (const float*)d_in[0];
  const float* ln1w = (const float*)d_in[1];
  const float* ln1b = (const float*)d_in[2];
  const float* ln2w = (const float*)d_in[3];
  const float* ln2b = (const float*)d_in[4];
  const float* win  = (const float*)d_in[5];
  const float* bin  = (const float*)d_in[6];
  const float* wout = (const float*)d_in[7];
  const float* bout = (const float*)d_in[8];
  const float* gw   = (const float*)d_in[9];
  // fc_w / fc_b / proj_w / proj_b (d_in[10..13]) are dead code in the reference.

  char* ws = (char*)d_ws;
  bf16*   w_in_b  = (bf16*)(ws);               // 6 MiB
  bf16*   w_out_b = (bf16*)(ws + 6291456);     // 2 MiB
  bf16*   h_b     = (bf16*)(ws + 8388608);     // 8 MiB (LN1 out; o_b aliases)
  ushort* o_b     = (ushort*)h_b;              // alias: h dead after GEMM1
  ushort* qkvb    = (ushort*)(ws + 16777216);  // q/k bf16 [bh][s][64]
  ushort* q_b     = qkvb;
  ushort* k_b     = qkvb + 4194304;
  float*  xnew    = (float*)(ws + 41943040);   // 16 MiB
  ushort* vt_b    = (ushort*)(ws + 58720256);  // 8 MiB: V^T [bh][dh][s]
  // total ws use: 64 MiB

  float* out  = (float*)d_out;
  float* rlog = out + (size_t)T_DIM * D_DIM;

  prep_kernel<<<8192, 256, 0, stream>>>(x, ln1w, ln1b, h_b,
                                        win, w_in_b, wout, w_out_b);
  gemm_qkv<<<dim3(QKV_N / 128, T_DIM / 128), 256, 0, stream>>>(
      h_b, w_in_b, bin, qkvb, vt_b, D_DIM);
  attn_mfma<<<512, 512, 0, stream>>>(q_b, k_b, vt_b, o_b);
  gemm_out<<<dim3(D_DIM / 64, T_DIM / 128), 256, 0, stream>>>(
      (const bf16*)o_b, w_out_b, bout, x, xnew);
  final_kernel<<<T_DIM, 256, 0, stream>>>(xnew, ln2w, ln2b, gw, out, rlog);
}

// Round 14
// 114.434 us; speedup vs baseline: 1.0160x; 1.0160x over previous
//
#include <hip/hip_runtime.h>
#include <hip/hip_bf16.h>

#define S_DIM 1024
#define B_DIM 4
#define D_DIM 1024
#define H_DIM 16
#define DH    64
#define T_DIM (S_DIM * B_DIM)   // 4096
#define QKV_N (3 * D_DIM)       // 3072

using bf16 = __hip_bfloat16;
typedef __attribute__((ext_vector_type(4))) float fx4;
typedef __attribute__((ext_vector_type(8))) short bx8;

__device__ __forceinline__ unsigned short f2bf(float f) {
  union { float f; unsigned int u; } cv; cv.f = f;
  unsigned int u = cv.u;
  unsigned int r = (u + 0x7FFFu + ((u >> 16) & 1u)) >> 16;  // RNE
  return (unsigned short)r;
}

__device__ __forceinline__ float bf2f(unsigned short u) {
  union { unsigned int u; float f; } cv; cv.u = ((unsigned int)u) << 16;
  return cv.f;
}

__device__ __forceinline__ void g2l16(const void* g, void* l) {
  __builtin_amdgcn_global_load_lds(
      (const __attribute__((address_space(1))) unsigned int*)g,
      (__attribute__((address_space(3))) unsigned int*)l, 16, 0, 0);
}

// ---------------- prep: LN1->bf16 (blocks 0..4095) + weight casts ----------
__global__ __launch_bounds__(256) void prep_kernel(
    const float* __restrict__ x, const float* __restrict__ w,
    const float* __restrict__ bb, bf16* __restrict__ out,
    const float* __restrict__ win, bf16* __restrict__ winb,
    const float* __restrict__ wout, bf16* __restrict__ woutb) {
  const int blk = blockIdx.x, tid = threadIdx.x;
  if (blk >= 4096) {  // weight cast: 1048576 fx4 chunks total
    const int i = (blk - 4096) * 256 + tid;
    const float* src; bf16* dst; int j;
    if (i < 786432) { src = win; dst = winb; j = i; }
    else { src = wout; dst = woutb; j = i - 786432; }
    const fx4 v = ((const fx4*)src)[j];
    ushort4 u;
    u.x = f2bf(v[0]); u.y = f2bf(v[1]); u.z = f2bf(v[2]); u.w = f2bf(v[3]);
    ((ushort4*)dst)[j] = u;
    return;
  }
  const int t = blk;
  const fx4 v = ((const fx4*)(x + (size_t)t * D_DIM))[tid];
  float s  = v[0] + v[1] + v[2] + v[3];
  float ss = v[0]*v[0] + v[1]*v[1] + v[2]*v[2] + v[3]*v[3];
#pragma unroll
  for (int off = 32; off >= 1; off >>= 1) {
    s  += __shfl_xor(s, off);
    ss += __shfl_xor(ss, off);
  }
  __shared__ float red[8];
  const int wid = tid >> 6, lane = tid & 63;
  if (lane == 0) { red[wid] = s; red[4 + wid] = ss; }
  __syncthreads();
  s  = red[0] + red[1] + red[2] + red[3];
  ss = red[4] + red[5] + red[6] + red[7];
  const float mu = s * (1.f / D_DIM);
  const float rstd = rsqrtf(ss * (1.f / D_DIM) - mu * mu + 1e-5f);
  const fx4 wv = ((const fx4*)w)[tid];
  const fx4 bv = ((const fx4*)bb)[tid];
  ushort4 u;
  u.x = f2bf((v[0] - mu) * rstd * wv[0] + bv[0]);
  u.y = f2bf((v[1] - mu) * rstd * wv[1] + bv[1]);
  u.z = f2bf((v[2] - mu) * rstd * wv[2] + bv[2]);
  u.w = f2bf((v[3] - mu) * rstd * wv[3] + bv[3]);
  ((ushort4*)(out + (size_t)t * D_DIM))[tid] = u;
}

// ---------------- qkv GEMM: 128x128, 3-deep, ONE barrier/iter --------------
// Structural ceiling config (rounds 4/7/8/10: 39.3 us, conflicts 0).
__global__ __launch_bounds__(256, 3) void gemm_qkv(
    const bf16* __restrict__ A, const bf16* __restrict__ B,
    const float* __restrict__ bias, ushort* __restrict__ qkvb, int K) {
  __shared__ char sA[3][8192];
  __shared__ char sB[3][8192];
  const int tid  = threadIdx.x;
  const int brow = blockIdx.y * 128;
  const int bcol = blockIdx.x * 128;
  const int wid  = tid >> 6;
  const int lane = tid & 63;
  const int wr   = wid >> 1;
  const int wc   = wid & 1;
  const int fr   = lane & 15;
  const int fk   = lane >> 4;

  fx4 acc[4][4];
#pragma unroll
  for (int i = 0; i < 4; ++i)
#pragma unroll
    for (int j = 0; j < 4; ++j) acc[i][j] = 0.f;

  const int arow = tid >> 2;                       // 0..63
  const int gch  = (tid & 3) ^ ((arow >> 1) & 3);  // inverse-swizzled chunk

  auto stage = [&](int buf, int kt) {
#pragma unroll
    for (int is = 0; is < 2; ++is) {
      const int row = is * 64 + arow;
      g2l16(A + (size_t)(brow + row) * K + kt + gch * 8,
            sA[buf] + is * 4096 + tid * 16);
      g2l16(B + (size_t)(bcol + row) * K + kt + gch * 8,
            sB[buf] + is * 4096 + tid * 16);
    }
  };

  stage(0, 0);
  stage(1, 32);

  const int nk = K >> 5;   // 32
#pragma unroll 1
  for (int ki = 0; ki < nk; ++ki) {
    const int buf = ki % 3;
    if (ki + 1 < nk) {
      asm volatile("s_waitcnt vmcnt(4)" ::: "memory");   // tile ki landed
    } else {
      asm volatile("s_waitcnt vmcnt(0)" ::: "memory");
    }
    __builtin_amdgcn_s_barrier();   // collective + WAR for buf[(ki+2)%3]
    asm volatile("" ::: "memory");
    if (ki + 2 < nk) stage((ki + 2) % 3, (ki + 2) * 32);

    bx8 af[4], bfr[4];
#pragma unroll
    for (int mm = 0; mm < 4; ++mm) {
      const int ar = wr * 64 + mm * 16 + fr;
      af[mm] = *(const bx8*)(sA[buf] + ar * 64 + ((fk ^ ((ar >> 1) & 3)) << 4));
    }
#pragma unroll
    for (int nn = 0; nn < 4; ++nn) {
      const int br = wc * 64 + nn * 16 + fr;
      bfr[nn] = *(const bx8*)(sB[buf] + br * 64 + ((fk ^ ((br >> 1) & 3)) << 4));
    }
    __builtin_amdgcn_s_setprio(1);
#pragma unroll
    for (int mm = 0; mm < 4; ++mm)
#pragma unroll
      for (int nn = 0; nn < 4; ++nn)
        acc[mm][nn] = __builtin_amdgcn_mfma_f32_16x16x32_bf16(
            af[mm], bfr[nn], acc[mm][nn], 0, 0, 0);
    __builtin_amdgcn_s_setprio(0);
    asm volatile("" ::: "memory");
  }

  // C/D layout: col = lane&15, row = (lane>>4)*4 + reg
  const int row0 = brow + wr * 64 + fk * 4;
  const int col0 = bcol + wc * 64 + fr;
#pragma unroll
  for (int mm = 0; mm < 4; ++mm) {
#pragma unroll
    for (int nn = 0; nn < 4; ++nn) {
      const int col = col0 + nn * 16;
      const float bv = bias[col];
      const int which = col >> 10;          // 0=q 1=k 2=v
      const int rem   = col & 1023;
      const int hh    = rem >> 6;
      const int dh    = rem & 63;
      // q scaled by DH^-0.5 * log2(e): softmax runs in exp2 domain
      const float scale = (which == 0) ? 0.18033688f : 1.0f;
#pragma unroll
      for (int rr = 0; rr < 4; ++rr) {
        const int row = row0 + mm * 16 + rr;  // t = s*B + b
        const int ss2 = row >> 2, bb2 = row & 3;
        const float v = (acc[mm][nn][rr] + bv) * scale;
        qkvb[(size_t)which * 4194304 +
             ((size_t)(bb2 * 16 + hh)) * 65536 + (size_t)ss2 * 64 + dh] = f2bf(v);
      }
    }
  }
}

// ---------------- V [bh][s][64] -> V^T [bh][dh][1024] ----------------
__global__ __launch_bounds__(256) void transpose_v(
    const ushort* __restrict__ v, ushort* __restrict__ vt) {
  __shared__ ushort tile[64][65];
  const int g  = blockIdx.x;
  const int bh = g >> 4, st = g & 15;
  const int s0 = st * 64;
  const int tid = threadIdx.x;
  const int r  = tid >> 2;          // 0..63
  const int c0 = (tid & 3) * 16;    // 0,16,32,48
  const ushort* src = v + (size_t)bh * 65536 + (size_t)(s0 + r) * 64 + c0;
#pragma unroll
  for (int i = 0; i < 2; ++i) {
    const bx8 d = *(const bx8*)(src + i * 8);
#pragma unroll
    for (int j = 0; j < 8; ++j) tile[r][c0 + i * 8 + j] = (ushort)d[j];
  }
  __syncthreads();
  ushort* dst = vt + (size_t)bh * 65536 + (size_t)r * 1024 + s0 + c0;
  bx8 w0, w1;
#pragma unroll
  for (int j = 0; j < 8; ++j) {
    w0[j] = (short)tile[c0 + j][r];
    w1[j] = (short)tile[c0 + 8 + j][r];
  }
  *(bx8*)dst = w0;
  *(bx8*)(dst + 8) = w1;
}

// ---------------- MFMA flash attention: 2 q-tiles share K/V staging --------
// Round-10 config (best measured): waves 0-3 own q-tile pr, waves 4-7 own
// 15-pr; one K/VT stage per iter serves both tiles; grid 512 = 2 blocks/CU;
// bid&7 = bh&7 keeps each bh's K/V on one XCD L2. Swapped S^T = mfma(K,Q);
// exp2-domain softmax; truncating bf16 P-pack; counted-vmcnt; defer-max.
__global__ __launch_bounds__(512, 4) void attn_mfma(
    const ushort* __restrict__ qb, const ushort* __restrict__ kb,
    const ushort* __restrict__ vtb, ushort* __restrict__ ob) {
  __shared__ __align__(16) char sK[2][8192];
  __shared__ __align__(16) char sVT[2][8192];
  __shared__ __align__(16) char sP[16384];
  const int tid  = threadIdx.x;
  const int wid  = tid >> 6;        // 0..7
  const int lane = tid & 63;
  const int bid  = blockIdx.x;
  const int xcd  = bid & 7;
  const int r2   = bid >> 3;        // 0..63
  const int pr   = r2 & 7;
  const int bh   = (r2 >> 3) * 8 + xcd;
  const int b    = bh >> 4, h = bh & 15;
  const int fr   = lane & 15;
  const int fk   = lane >> 4;
  const size_t bhoff = (size_t)bh * 65536;
  char* const sPw = sP + wid * 2048;
  const int swp = (fr & 7) << 4;
  const int qt_max  = 15 - pr;
  const int qt_mine = (wid < 4) ? pr : qt_max;
  const int wid4 = wid & 3;

  auto stage = [&](int buf, int k0) {
    const int L    = tid * 16;
    const int row  = L >> 7;
    const int colb = (L & 127) ^ ((row & 7) << 4);
    g2l16(kb  + bhoff + (size_t)(k0 + row) * 64 + (colb >> 1), sK[buf]  + L);
    g2l16(vtb + bhoff + (size_t)row * 1024 + k0 + (colb >> 1), sVT[buf] + L);
  };

  const int q0w = qt_mine * 64 + wid4 * 16;
  const ushort* qp = qb + bhoff + (size_t)(q0w + fr) * 64;
  const bx8 qf0 = *(const bx8*)(qp + fk * 8);
  const bx8 qf1 = *(const bx8*)(qp + 32 + fk * 8);
  asm volatile("s_waitcnt vmcnt(0)" ::: "memory");  // exact vmcnt counting

  fx4 o4[4];
  float m = -3e38f, l = 0.f;
#pragma unroll
  for (int dt = 0; dt < 4; ++dt) o4[dt] = 0.f;

  stage(0, 0);   // 2 loads/thread outstanding

#pragma unroll 1
  for (int kbk = 0; kbk <= qt_max; ++kbk) {
    const int cur = kbk & 1;
    if (kbk < qt_max) {
      stage(cur ^ 1, (kbk + 1) * 64);                   // +2 -> 4 outstanding
      asm volatile("s_waitcnt vmcnt(2)" ::: "memory");  // cur's 2 landed
    } else {
      asm volatile("s_waitcnt vmcnt(0)" ::: "memory");
    }
    __builtin_amdgcn_s_barrier();
    asm volatile("" ::: "memory");

    if (kbk <= qt_mine) {   // wave-uniform guard; no barriers inside
      const char* sKc  = sK[cur];
      const char* sVTc = sVT[cur];

      // --- S^T = mfma(K, Q): s4[kt][rr] = S[key=kt*16+fk*4+rr][q=fr] ---
      fx4 s4[4];
      __builtin_amdgcn_s_setprio(1);
#pragma unroll
      for (int kt = 0; kt < 4; ++kt) {
        const int krow = kt * 16 + fr;
        const int sw   = (krow & 7) << 4;
        const bx8 kf0 = *(const bx8*)(sKc + krow * 128 + ((fk * 16) ^ sw));
        const bx8 kf1 = *(const bx8*)(sKc + krow * 128 + ((64 + fk * 16) ^ sw));
        fx4 z = {0.f, 0.f, 0.f, 0.f};
        z = __builtin_amdgcn_mfma_f32_16x16x32_bf16(kf0, qf0, z, 0, 0, 0);
        s4[kt] = __builtin_amdgcn_mfma_f32_16x16x32_bf16(kf1, qf1, z, 0, 0, 0);
      }
      __builtin_amdgcn_s_setprio(0);

      if (kbk == qt_mine) {  // diagonal: wave-relative causal mask
        const int qloc = wid4 * 16 + fr;
#pragma unroll
        for (int kt = 0; kt < 4; ++kt) {
          const int keyb = kt * 16 + fk * 4;
#pragma unroll
          for (int rr = 0; rr < 4; ++rr)
            if (keyb + rr > qloc) s4[kt][rr] = -3e38f;
        }
      }

      // --- online softmax in exp2 domain: lane owns q=fr ---
      float pm = s4[0][0];
#pragma unroll
      for (int kt = 0; kt < 4; ++kt)
#pragma unroll
        for (int rr = 0; rr < 4; ++rr) pm = fmaxf(pm, s4[kt][rr]);
      pm = fmaxf(pm, __shfl_xor(pm, 16));
      pm = fmaxf(pm, __shfl_xor(pm, 32));

      if (__any(pm > m + 11.5f)) {   // defer-max (T13)
        const float mn = fmaxf(m, pm);
        const float f  = exp2f(m - mn);
        m = mn;
        l *= f;
        float fq[4];
#pragma unroll
        for (int rr = 0; rr < 4; ++rr) fq[rr] = __shfl(f, fk * 4 + rr);
#pragma unroll
        for (int dt = 0; dt < 4; ++dt)
#pragma unroll
          for (int rr = 0; rr < 4; ++rr) o4[dt][rr] *= fq[rr];
      }

      // --- P = exp2(S-m), truncating bf16 pack, b64 LDS writes ---
#pragma unroll
      for (int kt = 0; kt < 4; ++kt) {
        union { float f; unsigned u; } a0, a1, a2, a3;
        a0.f = exp2f(s4[kt][0] - m);
        a1.f = exp2f(s4[kt][1] - m);
        a2.f = exp2f(s4[kt][2] - m);
        a3.f = exp2f(s4[kt][3] - m);
        l += (a0.f + a1.f) + (a2.f + a3.f);
        uint2 pk;
        pk.x = (a0.u >> 16) | (a1.u & 0xFFFF0000u);
        pk.y = (a2.u >> 16) | (a3.u & 0xFFFF0000u);
        *(uint2*)(sPw + ((fr * 128 + kt * 32 + fk * 8) ^ swp)) = pk;
      }

      // --- O += P V ---
      __builtin_amdgcn_s_setprio(1);
#pragma unroll
      for (int c = 0; c < 2; ++c) {
        const bx8 pa = *(const bx8*)(sPw + ((fr * 128 + c * 64 + fk * 16) ^ swp));
#pragma unroll
        for (int dt = 0; dt < 4; ++dt) {
          const int vrow = dt * 16 + fr;
          const bx8 vf = *(const bx8*)(sVTc + vrow * 128 +
                                       ((c * 64 + fk * 16) ^ ((vrow & 7) << 4)));
          o4[dt] = __builtin_amdgcn_mfma_f32_16x16x32_bf16(pa, vf, o4[dt], 0, 0, 0);
        }
      }
      __builtin_amdgcn_s_setprio(0);
    }

    asm volatile("" ::: "memory");
    __builtin_amdgcn_s_barrier();   // readers done before next overwrite
    asm volatile("" ::: "memory");
  }

  // --- epilogue: total row sums, per-output-row norms, store ---
  l += __shfl_xor(l, 16);
  l += __shfl_xor(l, 32);
  const float linv = 1.f / l;
  float lq[4];
#pragma unroll
  for (int rr = 0; rr < 4; ++rr) lq[rr] = __shfl(linv, fk * 4 + rr);

#pragma unroll
  for (int dt = 0; dt < 4; ++dt) {
#pragma unroll
    for (int rr = 0; rr < 4; ++rr) {
      const int qq = q0w + fk * 4 + rr;
      ob[((size_t)qq * 4 + b) * 1024 + h * 64 + dt * 16 + fr] =
          f2bf(o4[dt][rr] * lq[rr]);
    }
  }
}

// ---------------- out-proj GEMM: 128x64, 3-deep, ONE barrier/iter ----------
// xnew now stored as bf16 (halves write traffic; final reads bf16).
__global__ __launch_bounds__(256, 2) void gemm_out(
    const bf16* __restrict__ A, const bf16* __restrict__ B,
    const float* __restrict__ bias, const float* __restrict__ resid,
    ushort* __restrict__ C) {
  __shared__ char sA[3][8192];
  __shared__ char sB[3][4096];
  const int tid  = threadIdx.x;
  const int brow = blockIdx.y * 128;
  const int bcol = blockIdx.x * 64;
  const int wid  = tid >> 6;
  const int lane = tid & 63;
  const int wr   = wid >> 1;      // 0..1: 64-row stripe
  const int wc   = wid & 1;       // 0..1: 32-col stripe
  const int fr   = lane & 15;
  const int fk   = lane >> 4;

  fx4 acc[4][2];
#pragma unroll
  for (int i = 0; i < 4; ++i)
#pragma unroll
    for (int j = 0; j < 2; ++j) acc[i][j] = 0.f;

  const int arow = tid >> 2;
  const int gch  = (tid & 3) ^ ((arow >> 1) & 3);

  auto stage = [&](int buf, int kt) {
#pragma unroll
    for (int is = 0; is < 2; ++is) {
      const int row = is * 64 + arow;
      g2l16(A + (size_t)(brow + row) * 1024 + kt + gch * 8,
            sA[buf] + is * 4096 + tid * 16);
    }
    g2l16(B + (size_t)(bcol + arow) * 1024 + kt + gch * 8,
          sB[buf] + tid * 16);
  };

  stage(0, 0);
  stage(1, 32);

#pragma unroll 1
  for (int ki = 0; ki < 32; ++ki) {
    const int buf = ki % 3;
    if (ki + 1 < 32) {
      asm volatile("s_waitcnt vmcnt(3)" ::: "memory");
    } else {
      asm volatile("s_waitcnt vmcnt(0)" ::: "memory");
    }
    __builtin_amdgcn_s_barrier();
    asm volatile("" ::: "memory");
    if (ki + 2 < 32) stage((ki + 2) % 3, (ki + 2) * 32);

    bx8 af[4], bfr[2];
#pragma unroll
    for (int mm = 0; mm < 4; ++mm) {
      const int ar = wr * 64 + mm * 16 + fr;
      af[mm] = *(const bx8*)(sA[buf] + ar * 64 + ((fk ^ ((ar >> 1) & 3)) << 4));
    }
#pragma unroll
    for (int nn = 0; nn < 2; ++nn) {
      const int br = wc * 32 + nn * 16 + fr;
      bfr[nn] = *(const bx8*)(sB[buf] + br * 64 + ((fk ^ ((br >> 1) & 3)) << 4));
    }
    __builtin_amdgcn_s_setprio(1);
#pragma unroll
    for (int mm = 0; mm < 4; ++mm)
#pragma unroll
      for (int nn = 0; nn < 2; ++nn)
        acc[mm][nn] = __builtin_amdgcn_mfma_f32_16x16x32_bf16(
            af[mm], bfr[nn], acc[mm][nn], 0, 0, 0);
    __builtin_amdgcn_s_setprio(0);
    asm volatile("" ::: "memory");
  }

  const int row0 = brow + wr * 64 + fk * 4;
  const int col0 = bcol + wc * 32 + fr;
#pragma unroll
  for (int mm = 0; mm < 4; ++mm) {
#pragma unroll
    for (int nn = 0; nn < 2; ++nn) {
      const int col = col0 + nn * 16;
      const float bv = bias[col];
#pragma unroll
      for (int rr = 0; rr < 4; ++rr) {
        const int row = row0 + mm * 16 + rr;
        C[(size_t)row * 1024 + col] =
            f2bf(acc[mm][nn][rr] + bv + resid[(size_t)row * 1024 + col]);
      }
    }
  }
}

// ---------------- LN2 + router + gate + final multiply (bf16 xnew) --------
__global__ __launch_bounds__(256) void final_kernel(
    const ushort* __restrict__ xn, const float* __restrict__ w,
    const float* __restrict__ bb, const float* __restrict__ gw,
    float* __restrict__ out, float* __restrict__ rlog) {
  const int t = blockIdx.x, tid = threadIdx.x;
  const ushort4 vb = ((const ushort4*)(xn + (size_t)t * D_DIM))[tid];
  fx4 v;
  v[0] = bf2f(vb.x); v[1] = bf2f(vb.y); v[2] = bf2f(vb.z); v[3] = bf2f(vb.w);
  float s  = v[0] + v[1] + v[2] + v[3];
  float ss = v[0]*v[0] + v[1]*v[1] + v[2]*v[2] + v[3]*v[3];
#pragma unroll
  for (int off = 32; off >= 1; off >>= 1) {
    s  += __shfl_xor(s, off);
    ss += __shfl_xor(ss, off);
  }
  __shared__ float red[8];
  __shared__ float red2[12];
  const int wid = tid >> 6, lane = tid & 63;
  if (lane == 0) { red[wid] = s; red[4 + wid] = ss; }
  __syncthreads();
  s  = red[0] + red[1] + red[2] + red[3];
  ss = red[4] + red[5] + red[6] + red[7];
  const float mu = s * (1.f / D_DIM);
  const float rstd = rsqrtf(ss * (1.f / D_DIM) - mu * mu + 1e-5f);
  const fx4 wv = ((const fx4*)w)[tid];
  const fx4 bv = ((const fx4*)bb)[tid];
  fx4 hv;
#pragma unroll
  for (int cc = 0; cc < 4; ++cc) hv[cc] = (v[cc] - mu) * rstd * wv[cc] + bv[cc];

  const fx4 w0 = ((const fx4*)(gw           ))[tid];
  const fx4 w1 = ((const fx4*)(gw +     D_DIM))[tid];
  const fx4 w2 = ((const fx4*)(gw + 2 * D_DIM))[tid];
  float g0 = hv[0]*w0[0] + hv[1]*w0[1] + hv[2]*w0[2] + hv[3]*w0[3];
  float g1 = hv[0]*w1[0] + hv[1]*w1[1] + hv[2]*w1[2] + hv[3]*w1[3];
  float g2 = hv[0]*w2[0] + hv[1]*w2[1] + hv[2]*w2[2] + hv[3]*w2[3];
#pragma unroll
  for (int off = 32; off >= 1; off >>= 1) {
    g0 += __shfl_xor(g0, off);
    g1 += __shfl_xor(g1, off);
    g2 += __shfl_xor(g2, off);
  }
  if (lane == 0) { red2[wid] = g0; red2[4 + wid] = g1; red2[8 + wid] = g2; }
  __syncthreads();
  g0 = red2[0] + red2[1] + red2[2]  + red2[3];
  g1 = red2[4] + red2[5] + red2[6]  + red2[7];
  g2 = red2[8] + red2[9] + red2[10] + red2[11];

  // gate = pmax/(pmax+p2nd) of softmax over 3 = 1/(1+exp(l_mid - l_max))
  const float lmax = fmaxf(g0, fmaxf(g1, g2));
  const float lmin = fminf(g0, fminf(g1, g2));
  const float lmid = (g0 + g1 + g2) - lmax - lmin;
  const float gate = 1.f / (1.f + __expf(lmid - lmax));

  ((fx4*)(out + (size_t)t * D_DIM))[tid] = v * gate;
  if (tid == 0) {
    rlog[(size_t)t * 3 + 0] = g0;
    rlog[(size_t)t * 3 + 1] = g1;
    rlog[(size_t)t * 3 + 2] = g2;
  }
}

extern "C" void kernel_launch(void* const* d_in, const int* in_sizes, int n_in,
                              void* d_out, int out_size, void* d_ws, size_t ws_size,
                              hipStream_t stream) {
  (void)in_sizes; (void)n_in; (void)out_size; (void)ws_size;
  const float* x    = (const float*)d_in[0];
  const float* ln1w = (const float*)d_in[1];
  const float* ln1b = (const float*)d_in[2];
  const float* ln2w = (const float*)d_in[3];
  const float* ln2b = (const float*)d_in[4];
  const float* win  = (const float*)d_in[5];
  const float* bin  = (const float*)d_in[6];
  const float* wout = (const float*)d_in[7];
  const float* bout = (const float*)d_in[8];
  const float* gw   = (const float*)d_in[9];
  // fc_w / fc_b / proj_w / proj_b (d_in[10..13]) are dead code in the reference.

  char* ws = (char*)d_ws;
  bf16*   w_in_b  = (bf16*)(ws);               // 6 MiB
  bf16*   w_out_b = (bf16*)(ws + 6291456);     // 2 MiB
  bf16*   h_b     = (bf16*)(ws + 8388608);     // 8 MiB (LN1 out; o_b aliases)
  ushort* o_b     = (ushort*)h_b;              // alias: h dead after GEMM1
  ushort* qkvb    = (ushort*)(ws + 16777216);  // 24 MiB: q/k/v bf16 [bh][s][64]
  ushort* q_b     = qkvb;
  ushort* k_b     = qkvb + 4194304;
  ushort* v_b     = qkvb + 8388608;
  ushort* xnew    = (ushort*)(ws + 41943040);  // 8 MiB (bf16)
  ushort* vt_b    = (ushort*)(ws + 58720256);  // 8 MiB: V^T [bh][dh][s]
  // total ws use: 64 MiB

  float* out  = (float*)d_out;
  float* rlog = out + (size_t)T_DIM * D_DIM;

  prep_kernel<<<8192, 256, 0, stream>>>(x, ln1w, ln1b, h_b,
                                        win, w_in_b, wout, w_out_b);
  gemm_qkv<<<dim3(QKV_N / 128, T_DIM / 128), 256, 0, stream>>>(
      h_b, w_in_b, bin, qkvb, D_DIM);
  transpose_v<<<1024, 256, 0, stream>>>(v_b, vt_b);
  attn_mfma<<<512, 512, 0, stream>>>(q_b, k_b, vt_b, o_b);
  gemm_out<<<dim3(D_DIM / 64, T_DIM / 128), 256, 0, stream>>>(
      (const bf16*)o_b, w_out_b, bout, x, xnew);
  final_kernel<<<T_DIM, 256, 0, stream>>>(xnew, ln2w, ln2b, gw, out, rlog);
}